// Round 6
// baseline (317.079 us; speedup 1.0000x reference)
//
#include <hip/hip_runtime.h>

// FlowNet correlation, kernel_size=1, max_disp=4.
// out[b, (dy+4)*9+(dx+4), y, x] = (1/C) * sum_c in1[b,c,y,x]*in2[b,c,y+dy,x+dx]
//
// R6 = R5 + T14 reg-prefetch double-buffering of the in2 staging.
// R5 counters showed clean traffic (spill fixed by acc[9][4]) but VALUBusy
// 18.7%: per-chunk global latency fully exposed (576-thr blocks don't
// co-reside -> no cross-block TLP). Fix: prefetch next chunk's in2 slots
// into registers BEFORE computing the current chunk; the ~4-5k cyc FMA
// phase hides the load latency. Live state now ~85 regs (R2's identical
// schedule spilled only because acc was 72 regs).
//   prefetch p(ch=0)
//   loop: sync; ds_write(p); sync; p=load(ch+1); compute(LDS)
// Tile 8x32, 9 waves (wave = dy), 576 thr. in1 read per-thread from
// global/L1 (9x wave reuse). s2 OOB/pad slots zeroed once, never rewritten.

#define BB 8
#define CC 96
#define HH 160
#define WW 320
#define TY 8
#define TX 32
#define CK 8
#define NCH (CC / CK)            // 12
#define HR (TY + 8)              // 16 halo rows
#define SW 44                    // LDS row stride floats (11 f4: 10 data + 1 pad)
#define NT 576
#define HW (HH * WW)
#define NSLOT (CK * HR * (SW / 4))   // 1408 f4 slots
#define NSTG 3                       // ceil(1408/576)

__global__ __launch_bounds__(NT, 2)
void corr_kernel(const float* __restrict__ in1,
                 const float* __restrict__ in2,
                 float* __restrict__ out) {
    const int x0 = blockIdx.x * TX;
    const int y0 = blockIdx.y * TY;
    const int b  = blockIdx.z;

    const int tid  = threadIdx.x;
    const int dy   = tid >> 6;       // 0..8, uniform per wave
    const int lane = tid & 63;
    const int yi   = lane >> 3;      // 0..7 output row in tile
    const int xt   = lane & 7;       // 0..7 -> 4-pixel x sub-block

    __shared__ __align__(16) float s2[CK][HR][SW];

    // ---- staging descriptors (once): f4-slot i = tid + t*NT ----
    int goff[NSTG];
    float4* lsl[NSTG];
    bool ok[NSTG];
#pragma unroll
    for (int t = 0; t < NSTG; ++t) {
        const int i = tid + t * NT;
        ok[t] = false; goff[t] = 0; lsl[t] = (float4*)&s2[0][0][0];
        if (i < NSLOT) {
            const int k = i / (HR * 11), rem = i % (HR * 11);
            const int r = rem / 11, c4 = rem % 11;
            lsl[t] = (float4*)&s2[k][r][4 * c4];
            const int yy = y0 + r - 4;
            const int xs = x0 - 4 + 4 * c4;
            if (c4 < 10 && (unsigned)yy < (unsigned)HH &&
                (unsigned)xs <= (unsigned)(WW - 4)) {
                ok[t] = true;
                goff[t] = (k * HH + yy) * WW + xs;
            }
        }
    }

    // ---- zero LDS once: OOB/pad slots stay zero across all chunks ----
    {
        const float4 z = make_float4(0.f, 0.f, 0.f, 0.f);
        float4* p = (float4*)&s2[0][0][0];
        for (int i = tid; i < NSLOT; i += NT) p[i] = z;
    }

    float acc[9][4];
#pragma unroll
    for (int i = 0; i < 9; ++i)
#pragma unroll
        for (int j = 0; j < 4; ++j) acc[i][j] = 0.0f;

    const float* in1p = in1 + ((size_t)(b * CC) * HH + y0 + yi) * WW + x0 + 4 * xt;

    // ---- prologue: prefetch chunk 0 into registers ----
    const float4 z4 = make_float4(0.f, 0.f, 0.f, 0.f);
    float4 p[NSTG];
    {
        const int cb = (b * CC) * HW;
#pragma unroll
        for (int t = 0; t < NSTG; ++t)
            p[t] = ok[t] ? *(const float4*)(in2 + cb + goff[t]) : z4;
    }

    for (int ch = 0; ch < NCH; ++ch) {
        __syncthreads();                     // all readers of prev chunk done
#pragma unroll
        for (int t = 0; t < NSTG; ++t)
            if (ok[t]) *lsl[t] = p[t];       // ds_write prefetched chunk
        __syncthreads();                     // chunk visible

        if (ch + 1 < NCH) {                  // issue next loads; latency hides
            const int cb = (b * CC + (ch + 1) * CK) * HW;   // under the FMAs
#pragma unroll
            for (int t = 0; t < NSTG; ++t)
                if (ok[t]) p[t] = *(const float4*)(in2 + cb + goff[t]);
        }

#pragma unroll
        for (int k = 0; k < CK; ++k) {
            float a[4];
            *(float4*)a = *(const float4*)(in1p + (size_t)(ch * CK + k) * HW);
            float v[12];
#pragma unroll
            for (int q = 0; q < 3; ++q)
                *(float4*)&v[4 * q] = *(const float4*)&s2[k][yi + dy][4 * xt + 4 * q];
#pragma unroll
            for (int dxi = 0; dxi < 9; ++dxi)
#pragma unroll
                for (int xi = 0; xi < 4; ++xi)
                    acc[dxi][xi] = fmaf(a[xi], v[xi + dxi], acc[dxi][xi]);
        }
    }

    // ---- epilogue: scale by 1/C, one float4 store per dx ----
    const float scale = 1.0f / (float)CC;
#pragma unroll
    for (int dxi = 0; dxi < 9; ++dxi) {
        float4 o = make_float4(acc[dxi][0] * scale, acc[dxi][1] * scale,
                               acc[dxi][2] * scale, acc[dxi][3] * scale);
        float* dst = out +
            (((size_t)(b * 81 + dy * 9 + dxi) * HH + y0 + yi) * WW + x0 + 4 * xt);
        *(float4*)dst = o;
    }
}

extern "C" void kernel_launch(void* const* d_in, const int* in_sizes, int n_in,
                              void* d_out, int out_size, void* d_ws, size_t ws_size,
                              hipStream_t stream) {
    const float* in1 = (const float*)d_in[0];
    const float* in2 = (const float*)d_in[1];
    float* out = (float*)d_out;
    dim3 grid(WW / TX, HH / TY, BB);  // 10 x 20 x 8 = 1600 blocks
    corr_kernel<<<grid, NT, 0, stream>>>(in1, in2, out);
}